// Round 1
// baseline (3838.183 us; speedup 1.0000x reference)
//
#include <hip/hip_runtime.h>
#include <float.h>

#define BB 2
#define LL 2048
#define EE 1024
#define HH 16
#define DHD 64
#define WIN 128

// out[m][n] = sum_k A[m][k] * W[n][k] + bias[n]   (x @ W^T + b)
// qkv_layout=1: dst indexed as [B,H,L,DH] with m=b*L+l, n=h*DH+d
__global__ __launch_bounds__(256) void gemm_nt(
    const float* __restrict__ A, const float* __restrict__ W,
    const float* __restrict__ bias, float* __restrict__ dst, int qkv_layout)
{
    __shared__ float As[32][33];
    __shared__ float Bs[32][33];
    const int tx = threadIdx.x;           // 0..31
    const int ty = threadIdx.y;           // 0..7
    const int row0 = blockIdx.y * 32;
    const int col0 = blockIdx.x * 32;
    float acc[4] = {0.f, 0.f, 0.f, 0.f};

    for (int k0 = 0; k0 < EE; k0 += 32) {
#pragma unroll
        for (int i = 0; i < 4; i++) {
            As[ty + 8*i][tx] = A[(size_t)(row0 + ty + 8*i) * EE + k0 + tx];
            Bs[ty + 8*i][tx] = W[(size_t)(col0 + ty + 8*i) * EE + k0 + tx];
        }
        __syncthreads();
#pragma unroll
        for (int kk = 0; kk < 32; kk++) {
            float bvv = Bs[tx][kk];
#pragma unroll
            for (int i = 0; i < 4; i++) acc[i] += As[ty + 8*i][kk] * bvv;
        }
        __syncthreads();
    }

    const int n = col0 + tx;
    const float bb = bias[n];
#pragma unroll
    for (int i = 0; i < 4; i++) {
        const int m = row0 + ty + 8*i;
        const float val = acc[i] + bb;
        if (qkv_layout) {
            const int b = m >> 11, l = m & (LL - 1);
            const int h = n >> 6,  d = n & 63;
            dst[((size_t)(b * HH + h) * LL + l) * DHD + d] = val;
        } else {
            dst[(size_t)m * EE + n] = val;
        }
    }
}

// One block (256 threads) per (b, h, query row i).
__global__ __launch_bounds__(256) void attn_kernel(
    const float* __restrict__ q, const float* __restrict__ k,
    const float* __restrict__ v, const float* __restrict__ pos_bias,
    float* __restrict__ attn_out)
{
    const int i = blockIdx.x;
    const int h = blockIdx.y;
    const int b = blockIdx.z;
    const int tid = threadIdx.x;

    __shared__ float sc[LL];
    __shared__ float qs[DHD];
    __shared__ float red[256];

    const size_t bh = (size_t)(b * HH + h) * LL;
    const float* qrow = q + (bh + i) * DHD;
    if (tid < DHD) qs[tid] = qrow[tid];
    for (int j = tid; j < LL; j += 256) sc[j] = -FLT_MAX;
    __syncthreads();

    // scores for allowed columns; gate (s>0) before bias; masked stays -FLT_MAX
    const float* kbase = k + bh * DHD;
    const float* pbrow = pos_bias + (size_t)i * LL;
    for (int j = tid; j < LL; j += 256) {
        const bool allowed = (i == 0) | (j == 0) |
                             ((j >= i - WIN) & (j <= i + WIN));
        if (!allowed) continue;
        const float* krow = kbase + (size_t)j * DHD;
        float s = 0.f;
#pragma unroll
        for (int d = 0; d < DHD; d++) s += qs[d] * krow[d];
        s *= 0.125f;                       // 1/sqrt(64)
        if (s > 0.0f) sc[j] = s + pbrow[j];
    }
    __syncthreads();

    // row max
    float m = -FLT_MAX;
    for (int j = tid; j < LL; j += 256) m = fmaxf(m, sc[j]);
    red[tid] = m;
    __syncthreads();
    for (int s = 128; s > 0; s >>= 1) {
        if (tid < s) red[tid] = fmaxf(red[tid], red[tid + s]);
        __syncthreads();
    }
    m = red[0];
    __syncthreads();

    // exp + sum (degenerate all-masked row -> all exp(0)=1 -> uniform, matches ref)
    float lsum = 0.f;
    for (int j = tid; j < LL; j += 256) {
        const float p = expf(sc[j] - m);
        sc[j] = p;
        lsum += p;
    }
    red[tid] = lsum;
    __syncthreads();
    for (int s = 128; s > 0; s >>= 1) {
        if (tid < s) red[tid] += red[tid + s];
        __syncthreads();
    }
    const float inv = 1.0f / red[0];
    __syncthreads();

    // PV: 64 dims x 4 j-partitions
    const int d = tid & 63;
    const int part = tid >> 6;
    float acc = 0.f;
    const float* vcol = v + bh * DHD + d;
    for (int j = part; j < LL; j += 4) {
        const float p = sc[j];
        if (p != 0.f) acc += p * vcol[(size_t)j * DHD];
    }
    red[tid] = acc;
    __syncthreads();
    if (tid < 64) {
        const float tot = (red[tid] + red[tid + 64]) +
                          (red[tid + 128] + red[tid + 192]);
        attn_out[((size_t)(b * LL + i)) * EE + h * DHD + tid] = tot * inv;
    }
}

extern "C" void kernel_launch(void* const* d_in, const int* in_sizes, int n_in,
                              void* d_out, int out_size, void* d_ws, size_t ws_size,
                              hipStream_t stream) {
    const float* x        = (const float*)d_in[0];
    const float* pos_bias = (const float*)d_in[1];
    const float* Wq = (const float*)d_in[2];
    const float* bq = (const float*)d_in[3];
    const float* Wk = (const float*)d_in[4];
    const float* bk = (const float*)d_in[5];
    const float* Wv = (const float*)d_in[6];
    const float* bv = (const float*)d_in[7];
    const float* Wo = (const float*)d_in[8];
    const float* bo = (const float*)d_in[9];
    float* out = (float*)d_out;

    const size_t QKV = (size_t)BB * HH * LL * DHD;   // 4,194,304 floats
    float* ws   = (float*)d_ws;
    float* q    = ws;
    float* k    = ws + QKV;
    float* v    = ws + 2 * QKV;
    float* attn = ws + 3 * QKV;                      // [B,L,E] layout

    dim3 blk(32, 8);
    dim3 g1(EE / 32, (BB * LL) / 32);
    gemm_nt<<<g1, blk, 0, stream>>>(x, Wq, bq, q, 1);
    gemm_nt<<<g1, blk, 0, stream>>>(x, Wk, bk, k, 1);
    gemm_nt<<<g1, blk, 0, stream>>>(x, Wv, bv, v, 1);

    attn_kernel<<<dim3(LL, HH, BB), 256, 0, stream>>>(q, k, v, pos_bias, attn);

    gemm_nt<<<g1, blk, 0, stream>>>(attn, Wo, bo, out, 0);
}

// Round 3
// 1930.094 us; speedup vs baseline: 1.9886x; 1.9886x over previous
//
#include <hip/hip_runtime.h>
#include <float.h>

#define BB 2
#define LL 2048
#define EE 1024
#define HH 16
#define DHD 64
#define WIN 128

// ---------------- GEMM: out = A @ W^T + bias (NT, both K-contiguous) --------
// A: [M, 1024], W: [N=1024, 1024] row-major. BM=BN=128, BK=16, 256 thr, 8x8.
// Double-buffered LDS with register prefetch.
__global__ __launch_bounds__(256) void gemm_nt_f32(
    const float* __restrict__ A, const float* __restrict__ W,
    const float* __restrict__ bias, float* __restrict__ dst, int qkv_layout)
{
    __shared__ float As[2][16][132];
    __shared__ float Bs[2][16][132];
    const int tid = threadIdx.x;
    const int tx = tid & 15, ty = tid >> 4;
    const int row0 = blockIdx.y * 128, col0 = blockIdx.x * 128;
    const int lr = tid >> 2;          // 0..63 (row within half-tile)
    const int lc = (tid & 3) * 4;     // k offset 0,4,8,12

    float acc[8][8];
#pragma unroll
    for (int i = 0; i < 8; i++)
#pragma unroll
        for (int j = 0; j < 8; j++) acc[i][j] = 0.f;

    // stage tile 0
#pragma unroll
    for (int it = 0; it < 2; it++) {
        const int r = lr + it * 64;
        float4 a = *(const float4*)&A[(size_t)(row0 + r) * EE + lc];
        As[0][lc + 0][r] = a.x; As[0][lc + 1][r] = a.y;
        As[0][lc + 2][r] = a.z; As[0][lc + 3][r] = a.w;
        float4 b = *(const float4*)&W[(size_t)(col0 + r) * EE + lc];
        Bs[0][lc + 0][r] = b.x; Bs[0][lc + 1][r] = b.y;
        Bs[0][lc + 2][r] = b.z; Bs[0][lc + 3][r] = b.w;
    }
    __syncthreads();

    int cur = 0;
    for (int t = 0; t < EE / 16; t++) {
        float4 pa[2], pb[2];
        const bool more = (t + 1) < EE / 16;
        if (more) {
            const int k0 = (t + 1) * 16;
#pragma unroll
            for (int it = 0; it < 2; it++) {
                const int r = lr + it * 64;
                pa[it] = *(const float4*)&A[(size_t)(row0 + r) * EE + k0 + lc];
                pb[it] = *(const float4*)&W[(size_t)(col0 + r) * EE + k0 + lc];
            }
        }
#pragma unroll
        for (int kk = 0; kk < 16; kk++) {
            float4 a0 = *(const float4*)&As[cur][kk][ty * 8];
            float4 a1 = *(const float4*)&As[cur][kk][ty * 8 + 4];
            float4 b0 = *(const float4*)&Bs[cur][kk][tx * 8];
            float4 b1 = *(const float4*)&Bs[cur][kk][tx * 8 + 4];
            float av[8] = {a0.x, a0.y, a0.z, a0.w, a1.x, a1.y, a1.z, a1.w};
            float bv[8] = {b0.x, b0.y, b0.z, b0.w, b1.x, b1.y, b1.z, b1.w};
#pragma unroll
            for (int i = 0; i < 8; i++)
#pragma unroll
                for (int j = 0; j < 8; j++) acc[i][j] += av[i] * bv[j];
        }
        if (more) {
            const int nb = cur ^ 1;
#pragma unroll
            for (int it = 0; it < 2; it++) {
                const int r = lr + it * 64;
                As[nb][lc + 0][r] = pa[it].x; As[nb][lc + 1][r] = pa[it].y;
                As[nb][lc + 2][r] = pa[it].z; As[nb][lc + 3][r] = pa[it].w;
                Bs[nb][lc + 0][r] = pb[it].x; Bs[nb][lc + 1][r] = pb[it].y;
                Bs[nb][lc + 2][r] = pb[it].z; Bs[nb][lc + 3][r] = pb[it].w;
            }
        }
        __syncthreads();
        cur ^= 1;
    }

#pragma unroll
    for (int i = 0; i < 8; i++) {
        const int m = row0 + ty * 8 + i;
#pragma unroll
        for (int j = 0; j < 8; j++) {
            const int n = col0 + tx * 8 + j;
            const float val = acc[i][j] + bias[n];
            if (qkv_layout) {
                const int b = m >> 11, l = m & (LL - 1);
                const int h = n >> 6, d = n & 63;
                dst[((size_t)(b * HH + h) * LL + l) * DHD + d] = val;
            } else {
                dst[(size_t)m * EE + n] = val;
            }
        }
    }
}

// ---------------- Windowed sparse attention ----------------
// One block (256 threads) per (b, h, query row i). Only the allowed column
// set is touched: {0} U [i-WIN, i+WIN]  (row 0: all columns).
__global__ __launch_bounds__(256) void attn_win(
    const float* __restrict__ q, const float* __restrict__ k,
    const float* __restrict__ v, const float* __restrict__ pos_bias,
    float* __restrict__ attn_out)
{
    const int i = blockIdx.x;
    const int h = blockIdx.y;
    const int b = blockIdx.z;
    const int tid = threadIdx.x;

    __shared__ float sc[LL];      // scores/probs by position (row 0 needs 2048)
    __shared__ float qs[DHD];
    __shared__ float red[256];

    const size_t bh = (size_t)(b * HH + h) * LL;
    if (tid < DHD) qs[tid] = q[(bh + i) * DHD + tid];

    // allowed-column mapping: position -> column
    int lo, ncols, extra;
    if (i == 0) { lo = 0; extra = 0; ncols = LL; }
    else {
        lo = (i - WIN > 0) ? i - WIN : 0;
        const int hi = (i + WIN < LL - 1) ? i + WIN : LL - 1;
        extra = (lo > 0) ? 1 : 0;              // column 0 prepended
        ncols = hi - lo + 1 + extra;
    }
    __syncthreads();

    // scores: gate (s > 0) before bias; gated-off -> -FLT_MAX (matches ref)
    const float* kbase = k + bh * DHD;
    const float* pbrow = pos_bias + (size_t)i * LL;
    for (int pos = tid; pos < ncols; pos += 256) {
        const int j = (extra && pos == 0) ? 0 : lo + pos - extra;
        const float4* kr = (const float4*)(kbase + (size_t)j * DHD);
        const float4* q4 = (const float4*)qs;
        float s = 0.f;
#pragma unroll
        for (int d4 = 0; d4 < 16; d4++) {
            const float4 kk4 = kr[d4];
            const float4 qq4 = q4[d4];
            s += qq4.x * kk4.x; s += qq4.y * kk4.y;
            s += qq4.z * kk4.z; s += qq4.w * kk4.w;
        }
        s *= 0.125f;                           // 1/sqrt(64)
        sc[pos] = (s > 0.0f) ? s + pbrow[j] : -FLT_MAX;
    }
    __syncthreads();

    // row max over positions
    float m = -FLT_MAX;
    for (int pos = tid; pos < ncols; pos += 256) m = fmaxf(m, sc[pos]);
    red[tid] = m;
    __syncthreads();
    for (int s = 128; s > 0; s >>= 1) {
        if (tid < s) red[tid] = fmaxf(red[tid], red[tid + s]);
        __syncthreads();
    }
    m = red[0];
    __syncthreads();

    // exp + sum
    float lsum = 0.f;
    for (int pos = tid; pos < ncols; pos += 256) {
        const float p = expf(sc[pos] - m);
        sc[pos] = p;
        lsum += p;
    }
    red[tid] = lsum;
    __syncthreads();
    for (int s = 128; s > 0; s >>= 1) {
        if (tid < s) red[tid] += red[tid + s];
        __syncthreads();
    }
    const float inv = 1.0f / red[0];
    __syncthreads();

    // PV over positions: 64 dims x 4 position-partitions
    const int d = tid & 63;
    const int part = tid >> 6;
    float acc = 0.f;
    const float* vcol = v + bh * DHD + d;
    for (int pos = part; pos < ncols; pos += 4) {
        const float p = sc[pos];
        if (p != 0.f) {
            const int j = (extra && pos == 0) ? 0 : lo + pos - extra;
            acc += p * vcol[(size_t)j * DHD];
        }
    }
    red[tid] = acc;
    __syncthreads();
    if (tid < 64) {
        const float tot = (red[tid] + red[tid + 64]) +
                          (red[tid + 128] + red[tid + 192]);
        attn_out[((size_t)(b * LL + i)) * EE + h * DHD + tid] = tot * inv;
    }
}

extern "C" void kernel_launch(void* const* d_in, const int* in_sizes, int n_in,
                              void* d_out, int out_size, void* d_ws, size_t ws_size,
                              hipStream_t stream) {
    const float* x        = (const float*)d_in[0];
    const float* pos_bias = (const float*)d_in[1];
    const float* Wq = (const float*)d_in[2];
    const float* bq = (const float*)d_in[3];
    const float* Wk = (const float*)d_in[4];
    const float* bk = (const float*)d_in[5];
    const float* Wv = (const float*)d_in[6];
    const float* bv = (const float*)d_in[7];
    const float* Wo = (const float*)d_in[8];
    const float* bo = (const float*)d_in[9];
    float* out = (float*)d_out;

    const size_t QKV = (size_t)BB * HH * LL * DHD;
    float* ws   = (float*)d_ws;
    float* q    = ws;
    float* k    = ws + QKV;
    float* v    = ws + 2 * QKV;
    float* attn = ws + 3 * QKV;                 // [B, L, E]

    dim3 blk(256);
    dim3 g1(EE / 128, (BB * LL) / 128);
    gemm_nt_f32<<<g1, blk, 0, stream>>>(x, Wq, bq, q, 1);
    gemm_nt_f32<<<g1, blk, 0, stream>>>(x, Wk, bk, k, 1);
    gemm_nt_f32<<<g1, blk, 0, stream>>>(x, Wv, bv, v, 1);

    attn_win<<<dim3(LL, HH, BB), 256, 0, stream>>>(q, k, v, pos_bias, attn);

    gemm_nt_f32<<<g1, blk, 0, stream>>>(attn, Wo, bo, out, 0);
}